// Round 5
// baseline (554.819 us; speedup 1.0000x reference)
//
#include <hip/hip_runtime.h>
#include <hip/hip_bf16.h>
#include <cstdint>
#include <cstddef>

#define Bdim 2
#define Tdim 2048
#define Ddim 2048
#define NHq  16
#define NKV  4
#define HD   128
// q is pre-scaled by SCALE*log2(e) at rope time; softmax uses exp2.
#define QSCALE 0.12751745f
#define NEG_INF (-3.0e38f)

typedef unsigned short u16;
typedef unsigned int   u32;
typedef __bf16 bf16x8 __attribute__((ext_vector_type(8)));
typedef float  f32x4  __attribute__((ext_vector_type(4)));

__device__ __forceinline__ u16 f2bf(float f) {
    unsigned int u = __float_as_uint(f);
    u += 0x7FFFu + ((u >> 16) & 1u);   // RNE
    return (u16)(u >> 16);
}
__device__ __forceinline__ float bf2f(u16 s) {
    return __uint_as_float(((unsigned int)s) << 16);
}
__device__ __forceinline__ u32 pack2bf(float a, float b) {
    union { __hip_bfloat162 h; u32 u; } cv;
    cv.h = __float22bfloat162_rn(make_float2(a, b));
    return cv.u;
}

// async global->LDS, 16B per lane. LDS dest is wave-uniform base + lane*16.
typedef __attribute__((address_space(1))) const u32 gbl_u32;
typedef __attribute__((address_space(3))) u32 lds_u32;
__device__ __forceinline__ void gload16(const void* g, void* l) {
    __builtin_amdgcn_global_load_lds((gbl_u32*)(uintptr_t)g, (lds_u32*)(uintptr_t)l, 16, 0, 0);
}

// ---------------------------------------------------------------------------
// fp32 -> bf16 straight convert for Xq, Xkv. 8 elems/thread.
// ---------------------------------------------------------------------------
__global__ __launch_bounds__(256) void cvt_x(const float* __restrict__ Xq,
                                             const float* __restrict__ Xkv,
                                             u16* __restrict__ oq,
                                             u16* __restrict__ okv)
{
    const size_t NE = (size_t)4096 * 2048 / 8;
    size_t idx = (size_t)blockIdx.x * 256 + threadIdx.x;
    const float* src; u16* dst; size_t off;
    if (idx < NE) { src = Xq;  dst = oq;  off = idx * 8; }
    else          { src = Xkv; dst = okv; off = (idx - NE) * 8; }
    float4 a = *(const float4*)&src[off];
    float4 b = *(const float4*)&src[off + 4];
    ushort4 r0, r1;
    r0.x = f2bf(a.x); r0.y = f2bf(a.y); r0.z = f2bf(a.z); r0.w = f2bf(a.w);
    r1.x = f2bf(b.x); r1.y = f2bf(b.y); r1.z = f2bf(b.z); r1.w = f2bf(b.w);
    *(ushort4*)&dst[off] = r0;
    *(ushort4*)&dst[off + 4] = r1;
}

// ---------------------------------------------------------------------------
// fp32 W[R][C] -> bf16 W^T[C][R], 64x64 LDS tiles. One launch, z selects W.
// ---------------------------------------------------------------------------
__global__ __launch_bounds__(256) void cvt_w_all(const float* __restrict__ Wq,
                                                 const float* __restrict__ Wk,
                                                 const float* __restrict__ Wv,
                                                 const float* __restrict__ Wo,
                                                 u16* __restrict__ wq_t,
                                                 u16* __restrict__ wk_t,
                                                 u16* __restrict__ wv_t,
                                                 u16* __restrict__ wo_t)
{
    __shared__ u16 t[64][72];
    const float* src; u16* dst; int C;
    switch (blockIdx.z) {
        case 0: src = Wq; dst = wq_t; C = 2048; break;
        case 1: src = Wk; dst = wk_t; C = 512;  break;
        case 2: src = Wv; dst = wv_t; C = 512;  break;
        default: src = Wo; dst = wo_t; C = 2048; break;
    }
    const int R = 2048;
    const int r0 = blockIdx.y * 64, c0 = blockIdx.x * 64;
    if (c0 >= C) return;
    const int tid = threadIdx.x;
    const int tr = tid >> 4, tc4 = (tid & 15) * 4;
#pragma unroll
    for (int p = 0; p < 4; p++) {
        int r = p * 16 + tr;
        float4 v = *(const float4*)&src[(size_t)(r0 + r) * C + c0 + tc4];
        t[tc4 + 0][r] = f2bf(v.x);
        t[tc4 + 1][r] = f2bf(v.y);
        t[tc4 + 2][r] = f2bf(v.z);
        t[tc4 + 3][r] = f2bf(v.w);
    }
    __syncthreads();
#pragma unroll
    for (int p = 0; p < 4; p++) {
        int cc = p * 16 + tr;
        ushort4 w = *(const ushort4*)&t[cc][tc4];
        *(ushort4*)&dst[(size_t)(c0 + cc) * R + r0 + tc4] = w;
    }
}

// ---------------------------------------------------------------------------
// bf16 MFMA GEMM mainloop (m97 structure)
// ---------------------------------------------------------------------------
__device__ __forceinline__ void bf16_gemm_mainloop(const u16* __restrict__ A,
                                                   const u16* __restrict__ Bt,
                                                   int m0, int n0,
                                                   u16 (&As)[128 * 32],
                                                   u16 (&Bs)[128 * 32],
                                                   f32x4 (&acc)[4][4])
{
    const int tid = threadIdx.x;
    const int wv = tid >> 6, lane = tid & 63;
    const int l15 = lane & 15, quad = lane >> 4;
    const int wr = wv >> 1, wc = wv & 1;

#pragma unroll
    for (int mt = 0; mt < 4; mt++)
#pragma unroll
        for (int nt = 0; nt < 4; nt++) acc[mt][nt] = (f32x4){0.f, 0.f, 0.f, 0.f};

    for (int k0 = 0; k0 < 2048; k0 += 32) {
        __syncthreads();
#pragma unroll
        for (int j = 0; j < 2; j++) {
            int c = wv * 128 + j * 64 + lane;
            const u16* ga = A + (size_t)(m0 + (c >> 2)) * 2048 + k0 + (c & 3) * 8;
            gload16(ga, &As[(wv * 128 + j * 64) * 8]);
            const u16* gb = Bt + (size_t)(n0 + (c >> 2)) * 2048 + k0 + (c & 3) * 8;
            gload16(gb, &Bs[(wv * 128 + j * 64) * 8]);
        }
        __syncthreads();

        bf16x8 af[4], bfr[4];
#pragma unroll
        for (int mt = 0; mt < 4; mt++)
            af[mt] = *(const bf16x8*)&As[(wr * 64 + mt * 16 + l15) * 32 + quad * 8];
#pragma unroll
        for (int nt = 0; nt < 4; nt++)
            bfr[nt] = *(const bf16x8*)&Bs[(wc * 64 + nt * 16 + l15) * 32 + quad * 8];
#pragma unroll
        for (int mt = 0; mt < 4; mt++)
#pragma unroll
            for (int nt = 0; nt < 4; nt++)
                acc[mt][nt] = __builtin_amdgcn_mfma_f32_16x16x32_bf16(af[mt], bfr[nt], acc[mt][nt], 0, 0, 0);
    }
}

// Fused QKV: grid (24, 32).
__global__ __launch_bounds__(256) void qkv_gemm_bf(const u16* __restrict__ Xq,
                                                   const u16* __restrict__ Xkv,
                                                   const u16* __restrict__ Wqt,
                                                   const u16* __restrict__ Wkt,
                                                   const u16* __restrict__ Wvt,
                                                   u16* __restrict__ qraw,
                                                   u16* __restrict__ kraw,
                                                   u16* __restrict__ vt)
{
    __shared__ __align__(16) u16 As[128 * 32];
    __shared__ __align__(16) u16 Bs[128 * 32];
    f32x4 acc[4][4];
    const int bx = blockIdx.x, m0 = blockIdx.y * 128;
    const u16 *A, *Bt; int n0;
    if (bx < 16)      { A = Xq;  Bt = Wqt; n0 = bx * 128; }
    else if (bx < 20) { A = Xkv; Bt = Wkt; n0 = (bx - 16) * 128; }
    else              { A = Xkv; Bt = Wvt; n0 = (bx - 20) * 128; }
    bf16_gemm_mainloop(A, Bt, m0, n0, As, Bs, acc);

    const int tid = threadIdx.x;
    const int wv = tid >> 6, lane = tid & 63;
    const int l15 = lane & 15, quad = lane >> 4;
    const int wr = wv >> 1, wc = wv & 1;

    if (bx < 20) {
        u16* out; int ldw;
        if (bx < 16) { out = qraw; ldw = 2048; }
        else         { out = kraw; ldw = 512; }
#pragma unroll
        for (int mt = 0; mt < 4; mt++)
#pragma unroll
            for (int nt = 0; nt < 4; nt++) {
                int col = n0 + wc * 64 + nt * 16 + l15;
                int r = m0 + wr * 64 + mt * 16 + quad * 4;
#pragma unroll
                for (int reg = 0; reg < 4; reg++)
                    out[(size_t)(r + reg) * ldw + col] = f2bf(acc[mt][nt][reg]);
            }
    } else {
        const int b = m0 >> 11, tb = m0 & 2047;
#pragma unroll
        for (int mt = 0; mt < 4; mt++)
#pragma unroll
            for (int nt = 0; nt < 4; nt++) {
                int col = n0 + wc * 64 + nt * 16 + l15;
                int tloc = tb + wr * 64 + mt * 16 + quad * 4;
                ushort4 w4;
                w4.x = f2bf(acc[mt][nt][0]);
                w4.y = f2bf(acc[mt][nt][1]);
                w4.z = f2bf(acc[mt][nt][2]);
                w4.w = f2bf(acc[mt][nt][3]);
                *(ushort4*)&vt[((size_t)b * 512 + col) * 2048 + tloc] = w4;
            }
    }
}

// Output projection: grid (16, 32).
__global__ __launch_bounds__(256) void oproj_gemm_bf(const u16* __restrict__ attnb,
                                                     const u16* __restrict__ Wot,
                                                     float* __restrict__ out)
{
    __shared__ __align__(16) u16 As[128 * 32];
    __shared__ __align__(16) u16 Bs[128 * 32];
    f32x4 acc[4][4];
    const int m0 = blockIdx.y * 128, n0 = blockIdx.x * 128;
    bf16_gemm_mainloop(attnb, Wot, m0, n0, As, Bs, acc);
    const int tid = threadIdx.x;
    const int wv = tid >> 6, lane = tid & 63;
    const int l15 = lane & 15, quad = lane >> 4;
    const int wr = wv >> 1, wc = wv & 1;
#pragma unroll
    for (int mt = 0; mt < 4; mt++)
#pragma unroll
        for (int nt = 0; nt < 4; nt++) {
            int col = n0 + wc * 64 + nt * 16 + l15;
            int r = m0 + wr * 64 + mt * 16 + quad * 4;
#pragma unroll
            for (int reg = 0; reg < 4; reg++)
                out[(size_t)(r + reg) * 2048 + col] = acc[mt][nt][reg];
        }
}

// ---------------------------------------------------------------------------
// In-place RoPE on bf16 q/k; q additionally scaled by QSCALE (softmax fold).
// Fast sin/cos via revolution range-reduction (v_rndne + native sin/cos).
// ---------------------------------------------------------------------------
__global__ __launch_bounds__(256) void rope_bf(u16* __restrict__ q,
                                               u16* __restrict__ k,
                                               const int* __restrict__ qpos,
                                               const int* __restrict__ kvpos)
{
    const int qTh = Bdim * Tdim * NHq * 16;
    int idx = blockIdx.x * 256 + threadIdx.x;
    u16* base; int h4; int pos; float oscale;
    if (idx < qTh) {
        int rn = idx >> 4; h4 = (idx & 15) * 4;
        pos = qpos[rn >> 4];
        base = q + (size_t)rn * HD;
        oscale = QSCALE;
    } else {
        int j = idx - qTh;
        int rn = j >> 4; h4 = (j & 15) * 4;
        pos = kvpos[rn >> 2];
        base = k + (size_t)rn * HD;
        oscale = 1.0f;
    }
    ushort4 a = *(const ushort4*)&base[h4];
    ushort4 bvec = *(const ushort4*)&base[h4 + 64];
    u16 av[4] = {a.x, a.y, a.z, a.w};
    u16 bv[4] = {bvec.x, bvec.y, bvec.z, bvec.w};
    const float fpos = (float)pos;
#pragma unroll
    for (int j = 0; j < 4; j++) {
        // inv timescale in revolutions: 10000^(-h/64) / (2*pi)
        float inv_ts_rev = exp2f(-(float)(h4 + j) * 0.2076205059f) * 0.15915494309f;
        float rev = fpos * inv_ts_rev;
        float r = rev - rintf(rev);          // [-0.5, 0.5]
        float ang = r * 6.2831853072f;       // [-pi, pi]
        float s = __sinf(ang), c = __cosf(ang);
        float x1 = bf2f(av[j]), x2 = bf2f(bv[j]);
        av[j] = f2bf((x1 * c - x2 * s) * oscale);
        bv[j] = f2bf((x2 * c + x1 * s) * oscale);
    }
    ushort4 ra, rb;
    ra.x = av[0]; ra.y = av[1]; ra.z = av[2]; ra.w = av[3];
    rb.x = bv[0]; rb.y = bv[1]; rb.z = bv[2]; rb.w = bv[3];
    *(ushort4*)&base[h4] = ra;
    *(ushort4*)&base[h4 + 64] = rb;
}

// ---------------------------------------------------------------------------
// Flash attention v3: BARRIER-FREE. BQ=128 (4 indep waves x 32 rows), BKV=64.
// K/V fragments direct from global (L2-hot); P via wave-private LDS region.
// q pre-scaled by SCALE*log2e -> softmax in exp2 domain.
// Grid (32 bh, 16 qt reversed).
// ---------------------------------------------------------------------------
__global__ __launch_bounds__(256, 3) void flash_attn_v3(const u16* __restrict__ qh,
                                                        const u16* __restrict__ kh,
                                                        const u16* __restrict__ vtg,
                                                        u16* __restrict__ attnb)
{
    // Ps[m][s]: physical chunk cb = (s>>3) ^ (m&7); wave-private rows.
    __shared__ __align__(16) u16 Ps[128 * 64];
    __shared__ float aArr[4][2][16];
    __shared__ float lArr[4][2][16];

    const int qt = 15 - (int)blockIdx.y;   // longest first
    const int bh = blockIdx.x;
    const int b = bh >> 4, n = bh & 15, kvh = n >> 2;
    const int q0 = qt * 128;
    const int tid = threadIdx.x;
    const int wv = tid >> 6, lane = tid & 63;
    const int l15 = lane & 15, quad = lane >> 4;

    // ---- Q fragments direct from global (B-operand: n=l15->m, k=quad*8+j->h) ----
    bf16x8 qfrag[2][4];
    {
        const size_t qbase = ((size_t)(b * Tdim + q0 + wv * 32)) * 2048 + n * 128;
#pragma unroll
        for (int mt = 0; mt < 2; mt++)
#pragma unroll
            for (int kt = 0; kt < 4; kt++)
                qfrag[mt][kt] = *(const bf16x8*)(qh + qbase + (size_t)(mt * 16 + l15) * 2048
                                                 + kt * 32 + quad * 8);
    }

    f32x4 Oacc[2][8];
#pragma unroll
    for (int mt = 0; mt < 2; mt++)
#pragma unroll
        for (int ht = 0; ht < 8; ht++) Oacc[mt][ht] = (f32x4){0.f, 0.f, 0.f, 0.f};
    float mrow[2] = {NEG_INF, NEG_INF};
    float lrow[2] = {0.f, 0.f};

    const u16* kbase = kh + (size_t)(b * Tdim) * 512 + kvh * 128;
    const u16* vbase = vtg + ((size_t)(b * 512 + kvh * 128)) * 2048;
    const int nT = 2 * qt + 2;

    for (int t = 0; t < nT; t++) {
        const int s0 = t * 64;

        // ---- S^T = K Q^T : K frags direct from global (A-op: m=l15->s) ----
        f32x4 S[2][4];
#pragma unroll
        for (int mt = 0; mt < 2; mt++)
#pragma unroll
            for (int nt = 0; nt < 4; nt++) S[mt][nt] = (f32x4){0.f, 0.f, 0.f, 0.f};
#pragma unroll
        for (int kt = 0; kt < 4; kt++) {
            bf16x8 kf[4];
#pragma unroll
            for (int nt = 0; nt < 4; nt++)
                kf[nt] = *(const bf16x8*)(kbase + (size_t)(s0 + nt * 16 + l15) * 512
                                          + kt * 32 + quad * 8);
#pragma unroll
            for (int mt = 0; mt < 2; mt++)
#pragma unroll
                for (int nt = 0; nt < 4; nt++)
                    S[mt][nt] = __builtin_amdgcn_mfma_f32_16x16x32_bf16(kf[nt], qfrag[mt][kt], S[mt][nt], 0, 0, 0);
        }

        // ---- online softmax in exp2 domain (q pre-scaled) ----
        const bool domask = (t >= nT - 2);
        float alph[2];
#pragma unroll
        for (int mt = 0; mt < 2; mt++) {
            const int m_l = wv * 32 + mt * 16 + l15;
            const int mg = q0 + m_l;
            float sv[16];
            float mx = NEG_INF;
#pragma unroll
            for (int nt = 0; nt < 4; nt++)
#pragma unroll
                for (int r = 0; r < 4; r++) {
                    float vv = S[mt][nt][r];
                    if (domask) {
                        int sg = s0 + nt * 16 + quad * 4 + r;
                        if (sg > mg) vv = NEG_INF;
                    }
                    sv[nt * 4 + r] = vv;
                    mx = fmaxf(mx, vv);
                }
            mx = fmaxf(mx, __shfl_xor(mx, 16));
            mx = fmaxf(mx, __shfl_xor(mx, 32));
            float mNew = fmaxf(mrow[mt], mx);
            alph[mt] = exp2f(mrow[mt] - mNew);
            mrow[mt] = mNew;
            float ps = 0.f;
#pragma unroll
            for (int i = 0; i < 16; i++) {
                float p = exp2f(sv[i] - mNew);
                sv[i] = p;
                ps += p;
            }
            ps += __shfl_xor(ps, 16);
            ps += __shfl_xor(ps, 32);
            lrow[mt] = lrow[mt] * alph[mt] + ps;
            // P row -> LDS (wave-private rows; packed bf16 cvt; 8B stores)
#pragma unroll
            for (int nt = 0; nt < 4; nt++) {
                int cb = (nt * 2 + (quad >> 1)) ^ (m_l & 7);
                uint2 pw;
                pw.x = pack2bf(sv[nt * 4 + 0], sv[nt * 4 + 1]);
                pw.y = pack2bf(sv[nt * 4 + 2], sv[nt * 4 + 3]);
                *(uint2*)&Ps[m_l * 64 + cb * 8 + (quad & 1) * 4] = pw;
            }
        }

        // ---- rescale O only when some row's max moved (usually not) ----
        if (!__all((alph[0] == 1.0f) & (alph[1] == 1.0f))) {
            if (quad == 0) {
                aArr[wv][0][l15] = alph[0];
                aArr[wv][1][l15] = alph[1];
            }
#pragma unroll
            for (int mt = 0; mt < 2; mt++) {
                f32x4 al4 = *(const f32x4*)&aArr[wv][mt][quad * 4];
#pragma unroll
                for (int ht = 0; ht < 8; ht++) {
                    Oacc[mt][ht][0] *= al4[0];
                    Oacc[mt][ht][1] *= al4[1];
                    Oacc[mt][ht][2] *= al4[2];
                    Oacc[mt][ht][3] *= al4[3];
                }
            }
        }

        // ---- O += P V : V frags direct from global (B-op: n=l15->h) ----
#pragma unroll
        for (int k2 = 0; k2 < 2; k2++) {
            bf16x8 pf[2];
#pragma unroll
            for (int mt = 0; mt < 2; mt++) {
                int m_l = wv * 32 + mt * 16 + l15;
                int cb = (k2 * 4 + quad) ^ (m_l & 7);
                pf[mt] = *(const bf16x8*)&Ps[m_l * 64 + cb * 8];
            }
#pragma unroll
            for (int ht = 0; ht < 8; ht++) {
                bf16x8 vf = *(const bf16x8*)(vbase + (size_t)(ht * 16 + l15) * 2048
                                             + s0 + k2 * 32 + quad * 8);
#pragma unroll
                for (int mt = 0; mt < 2; mt++)
                    Oacc[mt][ht] = __builtin_amdgcn_mfma_f32_16x16x32_bf16(pf[mt], vf, Oacc[mt][ht], 0, 0, 0);
            }
        }
    }

    // ---- epilogue (wave-private lArr broadcast; no barrier) ----
    if (quad == 0) {
        lArr[wv][0][l15] = lrow[0];
        lArr[wv][1][l15] = lrow[1];
    }
#pragma unroll
    for (int mt = 0; mt < 2; mt++) {
        f32x4 l4 = *(const f32x4*)&lArr[wv][mt][quad * 4];
        f32x4 inv;
        inv[0] = 1.0f / l4[0]; inv[1] = 1.0f / l4[1];
        inv[2] = 1.0f / l4[2]; inv[3] = 1.0f / l4[3];
        int mg0 = q0 + wv * 32 + mt * 16 + quad * 4;
        u16* dst0 = attnb + ((size_t)(b * Tdim + mg0)) * 2048 + n * 128 + l15;
#pragma unroll
        for (int ht = 0; ht < 8; ht++) {
#pragma unroll
            for (int r = 0; r < 4; r++)
                dst0[(size_t)r * 2048 + ht * 16] = f2bf(Oacc[mt][ht][r] * inv[r]);
        }
    }
}

extern "C" void kernel_launch(void* const* d_in, const int* in_sizes, int n_in,
                              void* d_out, int out_size, void* d_ws, size_t ws_size,
                              hipStream_t stream) {
    const float* Xq    = (const float*)d_in[0];
    const float* Xkv   = (const float*)d_in[1];
    const int*   qpos  = (const int*)d_in[2];
    const int*   kvpos = (const int*)d_in[3];
    const float* Wq    = (const float*)d_in[4];
    const float* Wk    = (const float*)d_in[5];
    const float* Wv    = (const float*)d_in[6];
    const float* Wo    = (const float*)d_in[7];
    float* out = (float*)d_out;

    char* w = (char*)d_ws;
    u16* xq_bf = (u16*)(w);                    // 16 MB
    u16* xkv_bf= (u16*)(w + (16u << 20));      // 16 MB
    u16* qraw  = (u16*)(w + (32u << 20));      // 16 MB (roped+scaled in place)
    u16* kraw  = (u16*)(w + (48u << 20));      //  4 MB (roped in place)
    u16* vt    = (u16*)(w + (52u << 20));      //  4 MB [(b*4+kvh)*128+h][2048]
    u16* wq_t  = (u16*)(w + (56u << 20));      //  8 MB
    u16* wk_t  = (u16*)(w + (64u << 20));      //  2 MB
    u16* wv_t  = (u16*)(w + (66u << 20));      //  2 MB
    u16* wo_t  = (u16*)(w + (68u << 20));      //  8 MB
    u16* attnb = (u16*)(w);                    // aliases xq_bf (dead by then)

    cvt_x<<<8192, 256, 0, stream>>>(Xq, Xkv, xq_bf, xkv_bf);
    cvt_w_all<<<dim3(32, 32, 4), 256, 0, stream>>>(Wq, Wk, Wv, Wo,
                                                   wq_t, wk_t, wv_t, wo_t);
    qkv_gemm_bf<<<dim3(24, 32), 256, 0, stream>>>(xq_bf, xkv_bf, wq_t, wk_t, wv_t,
                                                  qraw, kraw, vt);
    rope_bf<<<5120, 256, 0, stream>>>(qraw, kraw, qpos, kvpos);
    flash_attn_v3<<<dim3(32, 16), 256, 0, stream>>>(qraw, kraw, vt, attnb);
    oproj_gemm_bf<<<dim3(16, 32), 256, 0, stream>>>(attnb, wo_t, out);
}

// Round 6
// 493.436 us; speedup vs baseline: 1.1244x; 1.1244x over previous
//
#include <hip/hip_runtime.h>
#include <hip/hip_bf16.h>
#include <cstdint>
#include <cstddef>

#define Bdim 2
#define Tdim 2048
#define Ddim 2048
#define NHq  16
#define NKV  4
#define HD   128
// q is pre-scaled by SCALE*log2(e) at rope time; softmax uses exp2.
#define QSCALE 0.12751745f
#define NEG_INF (-3.0e38f)

typedef unsigned short u16;
typedef unsigned int   u32;
typedef __bf16 bf16x8 __attribute__((ext_vector_type(8)));
typedef float  f32x4  __attribute__((ext_vector_type(4)));

__device__ __forceinline__ u16 f2bf(float f) {
    unsigned int u = __float_as_uint(f);
    u += 0x7FFFu + ((u >> 16) & 1u);   // RNE
    return (u16)(u >> 16);
}
__device__ __forceinline__ float bf2f(u16 s) {
    return __uint_as_float(((unsigned int)s) << 16);
}
__device__ __forceinline__ u32 pack2bf(float a, float b) {
    union { __hip_bfloat162 h; u32 u; } cv;
    cv.h = __float22bfloat162_rn(make_float2(a, b));
    return cv.u;
}

// async global->LDS, 16B per lane. LDS dest is wave-uniform base + lane*16.
typedef __attribute__((address_space(1))) const u32 gbl_u32;
typedef __attribute__((address_space(3))) u32 lds_u32;
__device__ __forceinline__ void gload16(const void* g, void* l) {
    __builtin_amdgcn_global_load_lds((gbl_u32*)(uintptr_t)g, (lds_u32*)(uintptr_t)l, 16, 0, 0);
}

// ---------------------------------------------------------------------------
// fp32 -> bf16 straight convert for Xq, Xkv. 8 elems/thread.
// ---------------------------------------------------------------------------
__global__ __launch_bounds__(256) void cvt_x(const float* __restrict__ Xq,
                                             const float* __restrict__ Xkv,
                                             u16* __restrict__ oq,
                                             u16* __restrict__ okv)
{
    const size_t NE = (size_t)4096 * 2048 / 8;
    size_t idx = (size_t)blockIdx.x * 256 + threadIdx.x;
    const float* src; u16* dst; size_t off;
    if (idx < NE) { src = Xq;  dst = oq;  off = idx * 8; }
    else          { src = Xkv; dst = okv; off = (idx - NE) * 8; }
    float4 a = *(const float4*)&src[off];
    float4 b = *(const float4*)&src[off + 4];
    ushort4 r0, r1;
    r0.x = f2bf(a.x); r0.y = f2bf(a.y); r0.z = f2bf(a.z); r0.w = f2bf(a.w);
    r1.x = f2bf(b.x); r1.y = f2bf(b.y); r1.z = f2bf(b.z); r1.w = f2bf(b.w);
    *(ushort4*)&dst[off] = r0;
    *(ushort4*)&dst[off + 4] = r1;
}

// ---------------------------------------------------------------------------
// fp32 W[R][C] -> bf16 W^T[C][R], 64x64 LDS tiles. One launch, z selects W.
// ---------------------------------------------------------------------------
__global__ __launch_bounds__(256) void cvt_w_all(const float* __restrict__ Wq,
                                                 const float* __restrict__ Wk,
                                                 const float* __restrict__ Wv,
                                                 const float* __restrict__ Wo,
                                                 u16* __restrict__ wq_t,
                                                 u16* __restrict__ wk_t,
                                                 u16* __restrict__ wv_t,
                                                 u16* __restrict__ wo_t)
{
    __shared__ u16 t[64][72];
    const float* src; u16* dst; int C;
    switch (blockIdx.z) {
        case 0: src = Wq; dst = wq_t; C = 2048; break;
        case 1: src = Wk; dst = wk_t; C = 512;  break;
        case 2: src = Wv; dst = wv_t; C = 512;  break;
        default: src = Wo; dst = wo_t; C = 2048; break;
    }
    const int R = 2048;
    const int r0 = blockIdx.y * 64, c0 = blockIdx.x * 64;
    if (c0 >= C) return;
    const int tid = threadIdx.x;
    const int tr = tid >> 4, tc4 = (tid & 15) * 4;
#pragma unroll
    for (int p = 0; p < 4; p++) {
        int r = p * 16 + tr;
        float4 v = *(const float4*)&src[(size_t)(r0 + r) * C + c0 + tc4];
        t[tc4 + 0][r] = f2bf(v.x);
        t[tc4 + 1][r] = f2bf(v.y);
        t[tc4 + 2][r] = f2bf(v.z);
        t[tc4 + 3][r] = f2bf(v.w);
    }
    __syncthreads();
#pragma unroll
    for (int p = 0; p < 4; p++) {
        int cc = p * 16 + tr;
        ushort4 w = *(const ushort4*)&t[cc][tc4];
        *(ushort4*)&dst[(size_t)(c0 + cc) * R + r0 + tc4] = w;
    }
}

// ---------------------------------------------------------------------------
// bf16 MFMA GEMM mainloop (m97 structure)
// ---------------------------------------------------------------------------
__device__ __forceinline__ void bf16_gemm_mainloop(const u16* __restrict__ A,
                                                   const u16* __restrict__ Bt,
                                                   int m0, int n0,
                                                   u16 (&As)[128 * 32],
                                                   u16 (&Bs)[128 * 32],
                                                   f32x4 (&acc)[4][4])
{
    const int tid = threadIdx.x;
    const int wv = tid >> 6, lane = tid & 63;
    const int l15 = lane & 15, quad = lane >> 4;
    const int wr = wv >> 1, wc = wv & 1;

#pragma unroll
    for (int mt = 0; mt < 4; mt++)
#pragma unroll
        for (int nt = 0; nt < 4; nt++) acc[mt][nt] = (f32x4){0.f, 0.f, 0.f, 0.f};

    for (int k0 = 0; k0 < 2048; k0 += 32) {
        __syncthreads();
#pragma unroll
        for (int j = 0; j < 2; j++) {
            int c = wv * 128 + j * 64 + lane;
            const u16* ga = A + (size_t)(m0 + (c >> 2)) * 2048 + k0 + (c & 3) * 8;
            gload16(ga, &As[(wv * 128 + j * 64) * 8]);
            const u16* gb = Bt + (size_t)(n0 + (c >> 2)) * 2048 + k0 + (c & 3) * 8;
            gload16(gb, &Bs[(wv * 128 + j * 64) * 8]);
        }
        __syncthreads();

        bf16x8 af[4], bfr[4];
#pragma unroll
        for (int mt = 0; mt < 4; mt++)
            af[mt] = *(const bf16x8*)&As[(wr * 64 + mt * 16 + l15) * 32 + quad * 8];
#pragma unroll
        for (int nt = 0; nt < 4; nt++)
            bfr[nt] = *(const bf16x8*)&Bs[(wc * 64 + nt * 16 + l15) * 32 + quad * 8];
#pragma unroll
        for (int mt = 0; mt < 4; mt++)
#pragma unroll
            for (int nt = 0; nt < 4; nt++)
                acc[mt][nt] = __builtin_amdgcn_mfma_f32_16x16x32_bf16(af[mt], bfr[nt], acc[mt][nt], 0, 0, 0);
    }
}

// Fused QKV: grid (24, 32).
__global__ __launch_bounds__(256) void qkv_gemm_bf(const u16* __restrict__ Xq,
                                                   const u16* __restrict__ Xkv,
                                                   const u16* __restrict__ Wqt,
                                                   const u16* __restrict__ Wkt,
                                                   const u16* __restrict__ Wvt,
                                                   u16* __restrict__ qraw,
                                                   u16* __restrict__ kraw,
                                                   u16* __restrict__ vt)
{
    __shared__ __align__(16) u16 As[128 * 32];
    __shared__ __align__(16) u16 Bs[128 * 32];
    f32x4 acc[4][4];
    const int bx = blockIdx.x, m0 = blockIdx.y * 128;
    const u16 *A, *Bt; int n0;
    if (bx < 16)      { A = Xq;  Bt = Wqt; n0 = bx * 128; }
    else if (bx < 20) { A = Xkv; Bt = Wkt; n0 = (bx - 16) * 128; }
    else              { A = Xkv; Bt = Wvt; n0 = (bx - 20) * 128; }
    bf16_gemm_mainloop(A, Bt, m0, n0, As, Bs, acc);

    const int tid = threadIdx.x;
    const int wv = tid >> 6, lane = tid & 63;
    const int l15 = lane & 15, quad = lane >> 4;
    const int wr = wv >> 1, wc = wv & 1;

    if (bx < 20) {
        u16* out; int ldw;
        if (bx < 16) { out = qraw; ldw = 2048; }
        else         { out = kraw; ldw = 512; }
#pragma unroll
        for (int mt = 0; mt < 4; mt++)
#pragma unroll
            for (int nt = 0; nt < 4; nt++) {
                int col = n0 + wc * 64 + nt * 16 + l15;
                int r = m0 + wr * 64 + mt * 16 + quad * 4;
#pragma unroll
                for (int reg = 0; reg < 4; reg++)
                    out[(size_t)(r + reg) * ldw + col] = f2bf(acc[mt][nt][reg]);
            }
    } else {
        const int b = m0 >> 11, tb = m0 & 2047;
#pragma unroll
        for (int mt = 0; mt < 4; mt++)
#pragma unroll
            for (int nt = 0; nt < 4; nt++) {
                int col = n0 + wc * 64 + nt * 16 + l15;
                int tloc = tb + wr * 64 + mt * 16 + quad * 4;
                ushort4 w4;
                w4.x = f2bf(acc[mt][nt][0]);
                w4.y = f2bf(acc[mt][nt][1]);
                w4.z = f2bf(acc[mt][nt][2]);
                w4.w = f2bf(acc[mt][nt][3]);
                *(ushort4*)&vt[((size_t)b * 512 + col) * 2048 + tloc] = w4;
            }
    }
}

// Output projection: grid (16, 32).
__global__ __launch_bounds__(256) void oproj_gemm_bf(const u16* __restrict__ attnb,
                                                     const u16* __restrict__ Wot,
                                                     float* __restrict__ out)
{
    __shared__ __align__(16) u16 As[128 * 32];
    __shared__ __align__(16) u16 Bs[128 * 32];
    f32x4 acc[4][4];
    const int m0 = blockIdx.y * 128, n0 = blockIdx.x * 128;
    bf16_gemm_mainloop(attnb, Wot, m0, n0, As, Bs, acc);
    const int tid = threadIdx.x;
    const int wv = tid >> 6, lane = tid & 63;
    const int l15 = lane & 15, quad = lane >> 4;
    const int wr = wv >> 1, wc = wv & 1;
#pragma unroll
    for (int mt = 0; mt < 4; mt++)
#pragma unroll
        for (int nt = 0; nt < 4; nt++) {
            int col = n0 + wc * 64 + nt * 16 + l15;
            int r = m0 + wr * 64 + mt * 16 + quad * 4;
#pragma unroll
            for (int reg = 0; reg < 4; reg++)
                out[(size_t)(r + reg) * 2048 + col] = acc[mt][nt][reg];
        }
}

// ---------------------------------------------------------------------------
// In-place RoPE on bf16 q/k; q additionally scaled by QSCALE (softmax fold).
// Fast sin/cos via revolution range-reduction.
// ---------------------------------------------------------------------------
__global__ __launch_bounds__(256) void rope_bf(u16* __restrict__ q,
                                               u16* __restrict__ k,
                                               const int* __restrict__ qpos,
                                               const int* __restrict__ kvpos)
{
    const int qTh = Bdim * Tdim * NHq * 16;
    int idx = blockIdx.x * 256 + threadIdx.x;
    u16* base; int h4; int pos; float oscale;
    if (idx < qTh) {
        int rn = idx >> 4; h4 = (idx & 15) * 4;
        pos = qpos[rn >> 4];
        base = q + (size_t)rn * HD;
        oscale = QSCALE;
    } else {
        int j = idx - qTh;
        int rn = j >> 4; h4 = (j & 15) * 4;
        pos = kvpos[rn >> 2];
        base = k + (size_t)rn * HD;
        oscale = 1.0f;
    }
    ushort4 a = *(const ushort4*)&base[h4];
    ushort4 bvec = *(const ushort4*)&base[h4 + 64];
    u16 av[4] = {a.x, a.y, a.z, a.w};
    u16 bv[4] = {bvec.x, bvec.y, bvec.z, bvec.w};
    const float fpos = (float)pos;
#pragma unroll
    for (int j = 0; j < 4; j++) {
        // inv timescale in revolutions: 10000^(-h/64) / (2*pi)
        float inv_ts_rev = exp2f(-(float)(h4 + j) * 0.2076205059f) * 0.15915494309f;
        float rev = fpos * inv_ts_rev;
        float r = rev - rintf(rev);          // [-0.5, 0.5]
        float ang = r * 6.2831853072f;       // [-pi, pi]
        float s = __sinf(ang), c = __cosf(ang);
        float x1 = bf2f(av[j]), x2 = bf2f(bv[j]);
        av[j] = f2bf((x1 * c - x2 * s) * oscale);
        bv[j] = f2bf((x2 * c + x1 * s) * oscale);
    }
    ushort4 ra, rb;
    ra.x = av[0]; ra.y = av[1]; ra.z = av[2]; ra.w = av[3];
    rb.x = bv[0]; rb.y = bv[1]; rb.z = bv[2]; rb.w = bv[3];
    *(ushort4*)&base[h4] = ra;
    *(ushort4*)&base[h4 + 64] = rb;
}

// ---------------------------------------------------------------------------
// Flash attention v4: LDS-staged K/V (shared by 4 waves), transposed-S AND
// transposed-PV (O^T accumulator: column = q-row = lane's l15) so alpha/l are
// per-lane scalars. BQ=128 (4 waves x 32 rows), BKV=64. q pre-scaled; exp2.
// Grid (32 bh, 16 qt reversed).
// ---------------------------------------------------------------------------
__global__ __launch_bounds__(256, 3) void flash_attn_v4(const u16* __restrict__ qh,
                                                        const u16* __restrict__ kh,
                                                        const u16* __restrict__ vtg,
                                                        u16* __restrict__ attnb)
{
    // Ks[s][h]: physical col cb = c8 ^ (s&7)
    __shared__ __align__(16) u16 Ks[64 * 128];
    // Vt[h][s]: physical col cb = sb ^ (h&7)
    __shared__ __align__(16) u16 Vt[128 * 64];
    // Ps[m][s]: physical col cb = (s>>3) ^ (m&7); wave-private rows
    __shared__ __align__(16) u16 Ps[128 * 64];

    const int qt = 15 - (int)blockIdx.y;   // longest first
    const int bh = blockIdx.x;
    const int b = bh >> 4, n = bh & 15, kvh = n >> 2;
    const int q0 = qt * 128;
    const int tid = threadIdx.x;
    const int wv = tid >> 6, lane = tid & 63;
    const int l15 = lane & 15, quad = lane >> 4;

    // ---- Q fragments direct from global (B-operand: n=l15->m, k=quad*8+j->h) ----
    bf16x8 qfrag[2][4];
    {
        const size_t qbase = ((size_t)(b * Tdim + q0 + wv * 32)) * 2048 + n * 128;
#pragma unroll
        for (int mt = 0; mt < 2; mt++)
#pragma unroll
            for (int kt = 0; kt < 4; kt++)
                qfrag[mt][kt] = *(const bf16x8*)(qh + qbase + (size_t)(mt * 16 + l15) * 2048
                                                 + kt * 32 + quad * 8);
    }

    // O^T accumulator: D[m=h][n=q-row]; lane's column = q-row (l15), rows = h.
    f32x4 Oacc[2][8];
#pragma unroll
    for (int mt = 0; mt < 2; mt++)
#pragma unroll
        for (int ht = 0; ht < 8; ht++) Oacc[mt][ht] = (f32x4){0.f, 0.f, 0.f, 0.f};
    float mrow[2] = {NEG_INF, NEG_INF};
    float lrow[2] = {0.f, 0.f};

    const size_t kbase = (size_t)(b * Tdim) * 512 + kvh * 128;
    const size_t vbase = ((size_t)(b * 512 + kvh * 128)) * 2048;
    const int nT = 2 * qt + 2;

    for (int t = 0; t < nT; t++) {
        const int s0 = t * 64;
        __syncthreads();   // prev iter's frag reads done before overwrite
        // ---- stage K (16KB) and V (16KB) via global_load_lds, swizzled source ----
#pragma unroll
        for (int c = 0; c < 4; c++) {
            int j = c * 256 + tid;
            int s = j >> 4;
            int c8 = (j & 15) ^ (s & 7);
            gload16(kh + kbase + (size_t)(s0 + s) * 512 + c8 * 8,
                    &Ks[(c * 256 + wv * 64) * 8]);
            int h = j >> 3;
            int sb = (j & 7) ^ (h & 7);
            gload16(vtg + vbase + (size_t)h * 2048 + s0 + sb * 8,
                    &Vt[(c * 256 + wv * 64) * 8]);
        }
        __syncthreads();   // vmcnt drain before reads

        // ---- S^T = K Q^T : C/D col = q-row (l15), row = s (quad*4+r) ----
        f32x4 S[2][4];
#pragma unroll
        for (int mt = 0; mt < 2; mt++)
#pragma unroll
            for (int nt = 0; nt < 4; nt++) S[mt][nt] = (f32x4){0.f, 0.f, 0.f, 0.f};
#pragma unroll
        for (int kt = 0; kt < 4; kt++) {
            bf16x8 kf[4];
#pragma unroll
            for (int nt = 0; nt < 4; nt++) {
                int s = nt * 16 + l15;
                int cb = (kt * 4 + quad) ^ (s & 7);
                kf[nt] = *(const bf16x8*)&Ks[s * 128 + cb * 8];
            }
#pragma unroll
            for (int mt = 0; mt < 2; mt++)
#pragma unroll
                for (int nt = 0; nt < 4; nt++)
                    S[mt][nt] = __builtin_amdgcn_mfma_f32_16x16x32_bf16(kf[nt], qfrag[mt][kt], S[mt][nt], 0, 0, 0);
        }

        // ---- online softmax in exp2 domain; lane owns q-row l15 (per mt) ----
        const bool domask = (t >= nT - 2);
        float alph[2];
#pragma unroll
        for (int mt = 0; mt < 2; mt++) {
            const int m_l = wv * 32 + mt * 16 + l15;
            const int mg = q0 + m_l;
            float sv[16];
            float mx = NEG_INF;
#pragma unroll
            for (int nt = 0; nt < 4; nt++)
#pragma unroll
                for (int r = 0; r < 4; r++) {
                    float vv = S[mt][nt][r];
                    if (domask) {
                        int sg = s0 + nt * 16 + quad * 4 + r;
                        if (sg > mg) vv = NEG_INF;
                    }
                    sv[nt * 4 + r] = vv;
                    mx = fmaxf(mx, vv);
                }
            mx = fmaxf(mx, __shfl_xor(mx, 16));
            mx = fmaxf(mx, __shfl_xor(mx, 32));
            float mNew = fmaxf(mrow[mt], mx);
            alph[mt] = (mNew == mrow[mt]) ? 1.0f : exp2f(mrow[mt] - mNew);
            mrow[mt] = mNew;
            float ps = 0.f;
#pragma unroll
            for (int i = 0; i < 16; i++) {
                float p = exp2f(sv[i] - mNew);
                sv[i] = p;
                ps += p;
            }
            ps += __shfl_xor(ps, 16);
            ps += __shfl_xor(ps, 32);
            lrow[mt] = lrow[mt] * alph[mt] + ps;
            // P row -> LDS (wave-private rows; packed bf16; ds_write_b64)
#pragma unroll
            for (int nt = 0; nt < 4; nt++) {
                int cb = (nt * 2 + (quad >> 1)) ^ (m_l & 7);
                uint2 pw;
                pw.x = pack2bf(sv[nt * 4 + 0], sv[nt * 4 + 1]);
                pw.y = pack2bf(sv[nt * 4 + 2], sv[nt * 4 + 3]);
                *(uint2*)&Ps[m_l * 64 + cb * 8 + (quad & 1) * 4] = pw;
            }
        }

        // ---- rescale O^T by per-lane alpha (skip when uniformly 1) ----
        if (!__all((alph[0] == 1.0f) & (alph[1] == 1.0f))) {
#pragma unroll
            for (int mt = 0; mt < 2; mt++) {
                float a = alph[mt];
#pragma unroll
                for (int ht = 0; ht < 8; ht++) {
                    Oacc[mt][ht][0] *= a;
                    Oacc[mt][ht][1] *= a;
                    Oacc[mt][ht][2] *= a;
                    Oacc[mt][ht][3] *= a;
                }
            }
        }

        // ---- O^T += V^T P^T (operand-swapped PV; same frag reads as v2) ----
#pragma unroll
        for (int k2 = 0; k2 < 2; k2++) {
            bf16x8 pf[2];
#pragma unroll
            for (int mt = 0; mt < 2; mt++) {
                int m_l = wv * 32 + mt * 16 + l15;
                int cb = (k2 * 4 + quad) ^ (m_l & 7);
                pf[mt] = *(const bf16x8*)&Ps[m_l * 64 + cb * 8];
            }
#pragma unroll
            for (int ht = 0; ht < 8; ht++) {
                int h = ht * 16 + l15;
                int cb = (k2 * 4 + quad) ^ (h & 7);
                bf16x8 vf = *(const bf16x8*)&Vt[h * 64 + cb * 8];
#pragma unroll
                for (int mt = 0; mt < 2; mt++)
                    Oacc[mt][ht] = __builtin_amdgcn_mfma_f32_16x16x32_bf16(vf, pf[mt], Oacc[mt][ht], 0, 0, 0);
            }
        }
    }

    // ---- epilogue: per-lane 1/l; h is the C/D row dim -> ushort4 stores ----
#pragma unroll
    for (int mt = 0; mt < 2; mt++) {
        float inv = 1.0f / lrow[mt];
        int mg = q0 + wv * 32 + mt * 16 + l15;
        u16* dst = attnb + ((size_t)(b * Tdim + mg)) * 2048 + n * 128 + quad * 4;
#pragma unroll
        for (int ht = 0; ht < 8; ht++) {
            ushort4 o4;
            o4.x = f2bf(Oacc[mt][ht][0] * inv);
            o4.y = f2bf(Oacc[mt][ht][1] * inv);
            o4.z = f2bf(Oacc[mt][ht][2] * inv);
            o4.w = f2bf(Oacc[mt][ht][3] * inv);
            *(ushort4*)(dst + ht * 16) = o4;
        }
    }
}

extern "C" void kernel_launch(void* const* d_in, const int* in_sizes, int n_in,
                              void* d_out, int out_size, void* d_ws, size_t ws_size,
                              hipStream_t stream) {
    const float* Xq    = (const float*)d_in[0];
    const float* Xkv   = (const float*)d_in[1];
    const int*   qpos  = (const int*)d_in[2];
    const int*   kvpos = (const int*)d_in[3];
    const float* Wq    = (const float*)d_in[4];
    const float* Wk    = (const float*)d_in[5];
    const float* Wv    = (const float*)d_in[6];
    const float* Wo    = (const float*)d_in[7];
    float* out = (float*)d_out;

    char* w = (char*)d_ws;
    u16* xq_bf = (u16*)(w);                    // 16 MB
    u16* xkv_bf= (u16*)(w + (16u << 20));      // 16 MB
    u16* qraw  = (u16*)(w + (32u << 20));      // 16 MB (roped+scaled in place)
    u16* kraw  = (u16*)(w + (48u << 20));      //  4 MB (roped in place)
    u16* vt    = (u16*)(w + (52u << 20));      //  4 MB [(b*4+kvh)*128+h][2048]
    u16* wq_t  = (u16*)(w + (56u << 20));      //  8 MB
    u16* wk_t  = (u16*)(w + (64u << 20));      //  2 MB
    u16* wv_t  = (u16*)(w + (66u << 20));      //  2 MB
    u16* wo_t  = (u16*)(w + (68u << 20));      //  8 MB
    u16* attnb = (u16*)(w);                    // aliases xq_bf (dead by then)

    cvt_x<<<8192, 256, 0, stream>>>(Xq, Xkv, xq_bf, xkv_bf);
    cvt_w_all<<<dim3(32, 32, 4), 256, 0, stream>>>(Wq, Wk, Wv, Wo,
                                                   wq_t, wk_t, wv_t, wo_t);
    qkv_gemm_bf<<<dim3(24, 32), 256, 0, stream>>>(xq_bf, xkv_bf, wq_t, wk_t, wv_t,
                                                  qraw, kraw, vt);
    rope_bf<<<5120, 256, 0, stream>>>(qraw, kraw, qpos, kvpos);
    flash_attn_v4<<<dim3(32, 16), 256, 0, stream>>>(qraw, kraw, vt, attnb);
    oproj_gemm_bf<<<dim3(16, 32), 256, 0, stream>>>(attnb, wo_t, out);
}